// Round 5
// baseline (94.684 us; speedup 1.0000x reference)
//
#include <hip/hip_runtime.h>
#include <hip/hip_bf16.h>

// QuanvolutionGraphQLClassifier — f32 in/out. 2-kernel pipeline.
// Circuit factorizes into wires {0,1} x {2,3}; each Pauli-Z expectation is a
// bilinear form e_d = wA . H_d . wB with w(a) = (cos^2 a/2, cos a/2 sin a/2,
// sin^2 a/2) and H_d fixed 3x3 from q_params (verified R4: absmax matches
// full statevector path).
//  kA (196 blk x 64): build H (2 lanes), sample-0 measurements (LDS),
//      adjacency row m on the fly, fold into W2[k,4m+d]; block 0 exports H.
//  kB (B/4 blk x 256): one wave per sample; H+bias in regs; butterfly reduce;
//      log_softmax in regs.

#define NP 196

__device__ __forceinline__ float quad3(const float* H, const float* wa,
                                       const float* wb) {
  return wa[0] * (H[0] * wb[0] + H[1] * wb[1] + H[2] * wb[2]) +
         wa[1] * (H[3] * wb[0] + H[4] * wb[1] + H[5] * wb[2]) +
         wa[2] * (H[6] * wb[0] + H[7] * wb[1] + H[8] * wb[2]);
}

__device__ __forceinline__ void build_H(int t, const float* __restrict__ qp,
                                        float* __restrict__ Hs) {
  // t = 0 -> subsystem A (wires 0,1) -> Hs[0..17]; t = 1 -> B (2,3) -> Hs[18..35]
  float qc[6], qs[6];
#pragma unroll
  for (int i = 0; i < 6; ++i) sincosf(0.5f * qp[i], &qs[i], &qc[i]);
  float Mr[4][4] = {}, Mi[4][4] = {};
  if (t == 0) {
    // U_A = RY(q4,w0) * CNOT01 * RY(q1,w1) * RX(q0,w0); index = 2*b0 + b1
    Mr[0][0] = Mr[1][1] = Mr[2][2] = Mr[3][3] = qc[0];  // RX(q0) on w0
    Mi[0][2] = Mi[2][0] = Mi[1][3] = Mi[3][1] = -qs[0];
#pragma unroll
    for (int j = 0; j < 4; ++j) {  // RY(q1) on w1: rows (0,1),(2,3)
      float a, b;
      a = Mr[0][j]; b = Mr[1][j]; Mr[0][j] = qc[1]*a - qs[1]*b; Mr[1][j] = qs[1]*a + qc[1]*b;
      a = Mi[0][j]; b = Mi[1][j]; Mi[0][j] = qc[1]*a - qs[1]*b; Mi[1][j] = qs[1]*a + qc[1]*b;
      a = Mr[2][j]; b = Mr[3][j]; Mr[2][j] = qc[1]*a - qs[1]*b; Mr[3][j] = qs[1]*a + qc[1]*b;
      a = Mi[2][j]; b = Mi[3][j]; Mi[2][j] = qc[1]*a - qs[1]*b; Mi[3][j] = qs[1]*a + qc[1]*b;
    }
#pragma unroll
    for (int j = 0; j < 4; ++j) {  // CNOT(0,1): swap rows 2,3
      float r = Mr[2][j]; Mr[2][j] = Mr[3][j]; Mr[3][j] = r;
      float q = Mi[2][j]; Mi[2][j] = Mi[3][j]; Mi[3][j] = q;
    }
#pragma unroll
    for (int j = 0; j < 4; ++j) {  // RY(q4) on w0: rows (0,2),(1,3)
      float a, b;
      a = Mr[0][j]; b = Mr[2][j]; Mr[0][j] = qc[4]*a - qs[4]*b; Mr[2][j] = qs[4]*a + qc[4]*b;
      a = Mi[0][j]; b = Mi[2][j]; Mi[0][j] = qc[4]*a - qs[4]*b; Mi[2][j] = qs[4]*a + qc[4]*b;
      a = Mr[1][j]; b = Mr[3][j]; Mr[1][j] = qc[4]*a - qs[4]*b; Mr[3][j] = qs[4]*a + qc[4]*b;
      a = Mi[1][j]; b = Mi[3][j]; Mi[1][j] = qc[4]*a - qs[4]*b; Mi[3][j] = qs[4]*a + qc[4]*b;
    }
  } else {
    // U_B = RZ(q5,w3) * CNOT23 * RX(q3,w3) * RZ(q2,w2); index = 2*b2 + b3
    Mr[0][0] = Mr[1][1] = Mr[2][2] = Mr[3][3] = qc[2];  // RZ(q2) on w2
    Mi[0][0] = Mi[1][1] = -qs[2]; Mi[2][2] = Mi[3][3] = qs[2];
#pragma unroll
    for (int j = 0; j < 4; ++j) {  // RX(q3) on w3: rows (0,1),(2,3)
      float ra, ia, rb, ib;
      ra = Mr[0][j]; ia = Mi[0][j]; rb = Mr[1][j]; ib = Mi[1][j];
      Mr[0][j] = qc[3]*ra + qs[3]*ib;  Mi[0][j] = qc[3]*ia - qs[3]*rb;
      Mr[1][j] = qc[3]*rb + qs[3]*ia;  Mi[1][j] = qc[3]*ib - qs[3]*ra;
      ra = Mr[2][j]; ia = Mi[2][j]; rb = Mr[3][j]; ib = Mi[3][j];
      Mr[2][j] = qc[3]*ra + qs[3]*ib;  Mi[2][j] = qc[3]*ia - qs[3]*rb;
      Mr[3][j] = qc[3]*rb + qs[3]*ia;  Mi[3][j] = qc[3]*ib - qs[3]*ra;
    }
#pragma unroll
    for (int j = 0; j < 4; ++j) {  // CNOT(2,3): swap rows 2,3
      float r = Mr[2][j]; Mr[2][j] = Mr[3][j]; Mr[3][j] = r;
      float q = Mi[2][j]; Mi[2][j] = Mi[3][j]; Mi[3][j] = q;
    }
#pragma unroll
    for (int r = 0; r < 4; ++r) {  // RZ(q5) on w3: rows 0,2 *(c5-is5); 1,3 *(c5+is5)
      float sg = (r & 1) ? 1.0f : -1.0f;
#pragma unroll
      for (int j = 0; j < 4; ++j) {
        float re = Mr[r][j], im = Mi[r][j];
        Mr[r][j] = qc[5] * re - sg * qs[5] * im;
        Mi[r][j] = qc[5] * im + sg * qs[5] * re;
      }
    }
  }
  // G_d[j][k] = sum_i sigma_i (Re U_ij Re U_ik + Im U_ij Im U_ik)
#pragma unroll
  for (int d = 0; d < 2; ++d) {
    float G[4][4];
#pragma unroll
    for (int j = 0; j < 4; ++j)
#pragma unroll
      for (int k = 0; k < 4; ++k) {
        float g = 0.0f;
#pragma unroll
        for (int i = 0; i < 4; ++i) {
          float sg = (d == 0) ? ((i < 2) ? 1.f : -1.f)
                              : (((i & 1) == 0) ? 1.f : -1.f);
          g += sg * (Mr[i][j] * Mr[i][k] + Mi[i][j] * Mi[i][k]);
        }
        G[j][k] = g;
      }
    float* H = Hs + t * 18 + d * 9;
    H[0] = G[0][0];       H[1] = 2.f * G[0][1];               H[2] = G[1][1];
    H[3] = 2.f * G[0][2]; H[4] = 2.f * (G[0][3] + G[1][2]);   H[5] = 2.f * G[1][3];
    H[6] = G[2][2];       H[7] = 2.f * G[2][3];               H[8] = G[3][3];
  }
}

// Pauli-Z expectations of patch p of image xb, via the H bilinear forms.
template <int FAST>
__device__ __forceinline__ void meas_patch(const float* __restrict__ xb, int p,
                                           const float* __restrict__ H,
                                           float* e) {
  int i = p / 14, j = p - 14 * i;
  float2 top = *(const float2*)(xb + 56 * i + 2 * j);
  float2 bot = *(const float2*)(xb + 56 * i + 28 + 2 * j);
  float c0, s0, c1, s1, c2, s2, c3, s3;
  if (FAST) {
    __sincosf(0.5f * top.x, &s0, &c0);
    __sincosf(0.5f * top.y, &s1, &c1);
    __sincosf(0.5f * bot.x, &s2, &c2);
    __sincosf(0.5f * bot.y, &s3, &c3);
  } else {
    sincosf(0.5f * top.x, &s0, &c0);
    sincosf(0.5f * top.y, &s1, &c1);
    sincosf(0.5f * bot.x, &s2, &c2);
    sincosf(0.5f * bot.y, &s3, &c3);
  }
  float wA0[3] = {c0 * c0, c0 * s0, s0 * s0};
  float wA1[3] = {c1 * c1, c1 * s1, s1 * s1};
  float wB0[3] = {c2 * c2, c2 * s2, s2 * s2};
  float wB1[3] = {c3 * c3, c3 * s3, s3 * s3};
  e[0] = quad3(H, wA0, wA1);
  e[1] = quad3(H + 9, wA0, wA1);
  e[2] = quad3(H + 18, wB0, wB1);
  e[3] = quad3(H + 27, wB0, wB1);
}

// ---- kA: block m: H + sample-0 meas + adjacency row m -> W2[k,4m+d] -------
__global__ __launch_bounds__(64) void k_w2(const float* __restrict__ x,
                                           const float* __restrict__ qp,
                                           const float* __restrict__ W,
                                           float* __restrict__ W2,
                                           float* __restrict__ HG) {
  __shared__ float Hs[36];
  __shared__ float vs[NP][4];
  __shared__ float ns[NP];
  __shared__ float wrow[NP];
  int m = blockIdx.x, lane = threadIdx.x;
  if (lane < 2) build_H(lane, qp, Hs);
  __syncthreads();
  if (m == 0 && lane < 36) HG[lane] = Hs[lane];
  float H[36];
#pragma unroll
  for (int i = 0; i < 36; ++i) H[i] = Hs[i];
#pragma unroll
  for (int r = 0; r < 4; ++r) {
    int p = lane + 64 * r;
    if (p < NP) {
      float e[4];
      meas_patch<0>(x, p, H, e);
      vs[p][0] = e[0]; vs[p][1] = e[1]; vs[p][2] = e[2]; vs[p][3] = e[3];
      ns[p] = sqrtf(e[0]*e[0] + e[1]*e[1] + e[2]*e[2] + e[3]*e[3]);
    }
  }
  __syncthreads();
  float v0 = vs[m][0], v1 = vs[m][1], v2 = vs[m][2], v3 = vs[m][3];
  float nm = ns[m];
  for (int c = lane; c < NP; c += 64) {
    float dot = v0 * vs[c][0] + v1 * vs[c][1] + v2 * vs[c][2] + v3 * vs[c][3];
    float sim = dot / (nm * ns[c] + 1e-12f);  // symmetric => adj[c,m]
    wrow[c] = (sim >= 0.9f) ? 1.0f : ((sim >= 0.5f) ? 0.5f : 0.0f);
  }
  __syncthreads();
  if (lane < 40) {
    int k = lane >> 2, d = lane & 3;
    const float* Wk = W + k * 784 + d;
    float acc = 0.0f;
#pragma unroll 8
    for (int n = 0; n < NP; ++n) acc += wrow[n] * Wk[4 * n];
    W2[k * 784 + 4 * m + d] = acc;
  }
}

// ---- kB: one wave per sample ----------------------------------------------
__global__ __launch_bounds__(256) void k_main(const float* __restrict__ x,
                                              const float* __restrict__ HG,
                                              const float* __restrict__ bias,
                                              const float* __restrict__ W2,
                                              float* __restrict__ out, int Bsz) {
  int t = threadIdx.x, wv = t >> 6, lane = t & 63;
  int b = blockIdx.x * 4 + wv;
  if (b >= Bsz) return;

  float H[36];
#pragma unroll
  for (int i = 0; i < 36; ++i) H[i] = HG[i];  // uniform -> scalar loads
  float bv[10];
#pragma unroll
  for (int k = 0; k < 10; ++k) bv[k] = bias[k];

  const float* xb = x + (size_t)b * 784;
  float acc[10];
#pragma unroll
  for (int k = 0; k < 10; ++k) acc[k] = 0.0f;

#pragma unroll
  for (int r = 0; r < 4; ++r) {
    int p = lane + 64 * r;
    if (p < NP) {
      float e[4];
      meas_patch<1>(xb, p, H, e);
#pragma unroll
      for (int k = 0; k < 10; ++k) {
        float4 w = *(const float4*)(W2 + k * 784 + 4 * p);
        acc[k] += e[0] * w.x + e[1] * w.y + e[2] * w.z + e[3] * w.w;
      }
    }
  }
  // butterfly: every lane ends with all 10 totals
#pragma unroll
  for (int k = 0; k < 10; ++k)
#pragma unroll
    for (int off = 32; off; off >>= 1) acc[k] += __shfl_xor(acc[k], off);

  float lg[10], m = -1e30f;
#pragma unroll
  for (int k = 0; k < 10; ++k) { lg[k] = acc[k] + bv[k]; m = fmaxf(m, lg[k]); }
  float s = 0.0f;
#pragma unroll
  for (int k = 0; k < 10; ++k) s += __expf(lg[k] - m);
  float lse = m + __logf(s);
  if (lane < 10) {
    float sel = lg[0];
#pragma unroll
    for (int k = 1; k < 10; ++k) sel = (lane == k) ? lg[k] : sel;
    out[(size_t)b * 10 + lane] = sel - lse;
  }
}

extern "C" void kernel_launch(void* const* d_in, const int* in_sizes, int n_in,
                              void* d_out, int out_size, void* d_ws, size_t ws_size,
                              hipStream_t stream) {
  const float* x  = (const float*)d_in[0];  // (B,1,28,28) f32
  const float* qp = (const float*)d_in[1];  // (6,) f32
  const float* W  = (const float*)d_in[2];  // (10,784) f32
  const float* bi = (const float*)d_in[3];  // (10,) f32
  float* out = (float*)d_out;               // (B,10) f32

  int Bsz = in_sizes[0] / 784;

  float* W2 = (float*)d_ws;   // 7840 f32
  float* HG = W2 + 7840;      // 36 f32

  k_w2<<<NP, 64, 0, stream>>>(x, qp, W, W2, HG);
  k_main<<<(Bsz + 3) / 4, 256, 0, stream>>>(x, HG, bi, W2, out, Bsz);
}

// Round 6
// 93.193 us; speedup vs baseline: 1.0160x; 1.0160x over previous
//
#include <hip/hip_runtime.h>
#include <hip/hip_bf16.h>

// QuanvolutionGraphQLClassifier — f32 in/out. 2-kernel pipeline.
// Circuit factorizes into wires {0,1} x {2,3}; each Pauli-Z expectation is a
// bilinear form e_d = wA . H_d . wB with w(a) = (cos^2 a/2, cos a/2 sin a/2,
// sin^2 a/2) and H_d fixed 3x3 from q_params (verified R4/R5 vs statevector).
//  kA (196 blk x 64, lb(64,1)): all lanes build H redundantly in regs
//      (__sincosf, no spills), sample-0 meas -> LDS, adjacency row m on the
//      fly, fold into W2[k,4m+d]; block 0 lane 0 exports H.
//  kB (B/4 blk x 256, lb(256,2)): one wave per sample; butterfly reduce;
//      log_softmax in regs.
// R5 lesson: precise sincosf (OCML call) + VGPR-40 scratch spills made the
// prep path ~45 us in every prior round. __sincosf + (64,1) removes both.

#define NP 196

__device__ __forceinline__ float quad3(const float* H, const float* wa,
                                       const float* wb) {
  return wa[0] * (H[0] * wb[0] + H[1] * wb[1] + H[2] * wb[2]) +
         wa[1] * (H[3] * wb[0] + H[4] * wb[1] + H[5] * wb[2]) +
         wa[2] * (H[6] * wb[0] + H[7] * wb[1] + H[8] * wb[2]);
}

// Builds the full H[36] (A: 0..17, B: 18..35) — wave-uniform, all regs.
__device__ __forceinline__ void build_H_all(const float* __restrict__ qp,
                                            float* __restrict__ H) {
  float qc[6], qs[6];
#pragma unroll
  for (int i = 0; i < 6; ++i) __sincosf(0.5f * qp[i], &qs[i], &qc[i]);
#pragma unroll
  for (int sub = 0; sub < 2; ++sub) {
    float Mr[4][4] = {}, Mi[4][4] = {};
    if (sub == 0) {
      // U_A = RY(q4,w0) * CNOT01 * RY(q1,w1) * RX(q0,w0); index = 2*b0 + b1
      Mr[0][0] = Mr[1][1] = Mr[2][2] = Mr[3][3] = qc[0];  // RX(q0) on w0
      Mi[0][2] = Mi[2][0] = Mi[1][3] = Mi[3][1] = -qs[0];
#pragma unroll
      for (int j = 0; j < 4; ++j) {  // RY(q1) on w1: rows (0,1),(2,3)
        float a, b;
        a = Mr[0][j]; b = Mr[1][j]; Mr[0][j] = qc[1]*a - qs[1]*b; Mr[1][j] = qs[1]*a + qc[1]*b;
        a = Mi[0][j]; b = Mi[1][j]; Mi[0][j] = qc[1]*a - qs[1]*b; Mi[1][j] = qs[1]*a + qc[1]*b;
        a = Mr[2][j]; b = Mr[3][j]; Mr[2][j] = qc[1]*a - qs[1]*b; Mr[3][j] = qs[1]*a + qc[1]*b;
        a = Mi[2][j]; b = Mi[3][j]; Mi[2][j] = qc[1]*a - qs[1]*b; Mi[3][j] = qs[1]*a + qc[1]*b;
      }
#pragma unroll
      for (int j = 0; j < 4; ++j) {  // CNOT(0,1): swap rows 2,3
        float r = Mr[2][j]; Mr[2][j] = Mr[3][j]; Mr[3][j] = r;
        float q = Mi[2][j]; Mi[2][j] = Mi[3][j]; Mi[3][j] = q;
      }
#pragma unroll
      for (int j = 0; j < 4; ++j) {  // RY(q4) on w0: rows (0,2),(1,3)
        float a, b;
        a = Mr[0][j]; b = Mr[2][j]; Mr[0][j] = qc[4]*a - qs[4]*b; Mr[2][j] = qs[4]*a + qc[4]*b;
        a = Mi[0][j]; b = Mi[2][j]; Mi[0][j] = qc[4]*a - qs[4]*b; Mi[2][j] = qs[4]*a + qc[4]*b;
        a = Mr[1][j]; b = Mr[3][j]; Mr[1][j] = qc[4]*a - qs[4]*b; Mr[3][j] = qs[4]*a + qc[4]*b;
        a = Mi[1][j]; b = Mi[3][j]; Mi[1][j] = qc[4]*a - qs[4]*b; Mi[3][j] = qs[4]*a + qc[4]*b;
      }
    } else {
      // U_B = RZ(q5,w3) * CNOT23 * RX(q3,w3) * RZ(q2,w2); index = 2*b2 + b3
      Mr[0][0] = Mr[1][1] = Mr[2][2] = Mr[3][3] = qc[2];  // RZ(q2) on w2
      Mi[0][0] = Mi[1][1] = -qs[2]; Mi[2][2] = Mi[3][3] = qs[2];
#pragma unroll
      for (int j = 0; j < 4; ++j) {  // RX(q3) on w3: rows (0,1),(2,3)
        float ra, ia, rb, ib;
        ra = Mr[0][j]; ia = Mi[0][j]; rb = Mr[1][j]; ib = Mi[1][j];
        Mr[0][j] = qc[3]*ra + qs[3]*ib;  Mi[0][j] = qc[3]*ia - qs[3]*rb;
        Mr[1][j] = qc[3]*rb + qs[3]*ia;  Mi[1][j] = qc[3]*ib - qs[3]*ra;
        ra = Mr[2][j]; ia = Mi[2][j]; rb = Mr[3][j]; ib = Mi[3][j];
        Mr[2][j] = qc[3]*ra + qs[3]*ib;  Mi[2][j] = qc[3]*ia - qs[3]*rb;
        Mr[3][j] = qc[3]*rb + qs[3]*ia;  Mi[3][j] = qc[3]*ib - qs[3]*ra;
      }
#pragma unroll
      for (int j = 0; j < 4; ++j) {  // CNOT(2,3): swap rows 2,3
        float r = Mr[2][j]; Mr[2][j] = Mr[3][j]; Mr[3][j] = r;
        float q = Mi[2][j]; Mi[2][j] = Mi[3][j]; Mi[3][j] = q;
      }
#pragma unroll
      for (int r = 0; r < 4; ++r) {  // RZ(q5) on w3: rows 0,2 *(c5-is5); 1,3 *(c5+is5)
        float sg = (r & 1) ? 1.0f : -1.0f;
#pragma unroll
        for (int j = 0; j < 4; ++j) {
          float re = Mr[r][j], im = Mi[r][j];
          Mr[r][j] = qc[5] * re - sg * qs[5] * im;
          Mi[r][j] = qc[5] * im + sg * qs[5] * re;
        }
      }
    }
    // G_d[j][k] = sum_i sigma_i (Re U_ij Re U_ik + Im U_ij Im U_ik)
#pragma unroll
    for (int d = 0; d < 2; ++d) {
      float G[4][4];
#pragma unroll
      for (int j = 0; j < 4; ++j)
#pragma unroll
        for (int k = 0; k < 4; ++k) {
          float g = 0.0f;
#pragma unroll
          for (int i = 0; i < 4; ++i) {
            float sg = (d == 0) ? ((i < 2) ? 1.f : -1.f)
                                : (((i & 1) == 0) ? 1.f : -1.f);
            g += sg * (Mr[i][j] * Mr[i][k] + Mi[i][j] * Mi[i][k]);
          }
          G[j][k] = g;
        }
      float* Hd = H + sub * 18 + d * 9;
      Hd[0] = G[0][0];       Hd[1] = 2.f * G[0][1];               Hd[2] = G[1][1];
      Hd[3] = 2.f * G[0][2]; Hd[4] = 2.f * (G[0][3] + G[1][2]);   Hd[5] = 2.f * G[1][3];
      Hd[6] = G[2][2];       Hd[7] = 2.f * G[2][3];               Hd[8] = G[3][3];
    }
  }
}

// Pauli-Z expectations of patch p of image xb, via the H bilinear forms.
__device__ __forceinline__ void meas_patch(const float* __restrict__ xb, int p,
                                           const float* __restrict__ H,
                                           float* e) {
  int i = p / 14, j = p - 14 * i;
  float2 top = *(const float2*)(xb + 56 * i + 2 * j);
  float2 bot = *(const float2*)(xb + 56 * i + 28 + 2 * j);
  float c0, s0, c1, s1, c2, s2, c3, s3;
  __sincosf(0.5f * top.x, &s0, &c0);
  __sincosf(0.5f * top.y, &s1, &c1);
  __sincosf(0.5f * bot.x, &s2, &c2);
  __sincosf(0.5f * bot.y, &s3, &c3);
  float wA0[3] = {c0 * c0, c0 * s0, s0 * s0};
  float wA1[3] = {c1 * c1, c1 * s1, s1 * s1};
  float wB0[3] = {c2 * c2, c2 * s2, s2 * s2};
  float wB1[3] = {c3 * c3, c3 * s3, s3 * s3};
  e[0] = quad3(H, wA0, wA1);
  e[1] = quad3(H + 9, wA0, wA1);
  e[2] = quad3(H + 18, wB0, wB1);
  e[3] = quad3(H + 27, wB0, wB1);
}

// ---- kA: block m: H + sample-0 meas + adjacency row m -> W2[k,4m+d] -------
__global__ __launch_bounds__(64, 1) void k_w2(const float* __restrict__ x,
                                              const float* __restrict__ qp,
                                              const float* __restrict__ W,
                                              float* __restrict__ W2,
                                              float* __restrict__ HG) {
  __shared__ float vs[NP][4];
  __shared__ float ns[NP];
  __shared__ float wrow[NP];
  int m = blockIdx.x, lane = threadIdx.x;

  float H[36];
  build_H_all(qp, H);  // wave-uniform, registers only

  if (m == 0 && lane == 0) {
#pragma unroll
    for (int i = 0; i < 36; ++i) HG[i] = H[i];  // constant indices
  }

#pragma unroll
  for (int r = 0; r < 4; ++r) {
    int p = lane + 64 * r;
    if (p < NP) {
      float e[4];
      meas_patch(x, p, H, e);
      vs[p][0] = e[0]; vs[p][1] = e[1]; vs[p][2] = e[2]; vs[p][3] = e[3];
      ns[p] = sqrtf(e[0]*e[0] + e[1]*e[1] + e[2]*e[2] + e[3]*e[3]);
    }
  }
  __syncthreads();
  float v0 = vs[m][0], v1 = vs[m][1], v2 = vs[m][2], v3 = vs[m][3];
  float nm = ns[m];
  for (int c = lane; c < NP; c += 64) {
    float dot = v0 * vs[c][0] + v1 * vs[c][1] + v2 * vs[c][2] + v3 * vs[c][3];
    float sim = dot / (nm * ns[c] + 1e-12f);  // symmetric => adj[c,m]
    wrow[c] = (sim >= 0.9f) ? 1.0f : ((sim >= 0.5f) ? 0.5f : 0.0f);
  }
  __syncthreads();
  if (lane < 40) {
    int k = lane >> 2, d = lane & 3;
    const float* Wk = W + k * 784 + d;
    float acc = 0.0f;
#pragma unroll 8
    for (int n = 0; n < NP; ++n) acc += wrow[n] * Wk[4 * n];
    W2[k * 784 + 4 * m + d] = acc;
  }
}

// ---- kB: one wave per sample ----------------------------------------------
__global__ __launch_bounds__(256, 2) void k_main(const float* __restrict__ x,
                                                 const float* __restrict__ HG,
                                                 const float* __restrict__ bias,
                                                 const float* __restrict__ W2,
                                                 float* __restrict__ out,
                                                 int Bsz) {
  int t = threadIdx.x, wv = t >> 6, lane = t & 63;
  int b = blockIdx.x * 4 + wv;
  if (b >= Bsz) return;

  float H[36];
#pragma unroll
  for (int i = 0; i < 36; ++i) H[i] = HG[i];  // uniform -> scalar loads
  float bv[10];
#pragma unroll
  for (int k = 0; k < 10; ++k) bv[k] = bias[k];

  const float* xb = x + (size_t)b * 784;
  float acc[10];
#pragma unroll
  for (int k = 0; k < 10; ++k) acc[k] = 0.0f;

#pragma unroll
  for (int r = 0; r < 4; ++r) {
    int p = lane + 64 * r;
    if (p < NP) {
      float e[4];
      meas_patch(xb, p, H, e);
#pragma unroll
      for (int k = 0; k < 10; ++k) {
        float4 w = *(const float4*)(W2 + k * 784 + 4 * p);
        acc[k] += e[0] * w.x + e[1] * w.y + e[2] * w.z + e[3] * w.w;
      }
    }
  }
  // butterfly: every lane ends with all 10 totals
#pragma unroll
  for (int k = 0; k < 10; ++k)
#pragma unroll
    for (int off = 32; off; off >>= 1) acc[k] += __shfl_xor(acc[k], off);

  float lg[10], m = -1e30f;
#pragma unroll
  for (int k = 0; k < 10; ++k) { lg[k] = acc[k] + bv[k]; m = fmaxf(m, lg[k]); }
  float s = 0.0f;
#pragma unroll
  for (int k = 0; k < 10; ++k) s += __expf(lg[k] - m);
  float lse = m + __logf(s);
  if (lane < 10) {
    float sel = lg[0];
#pragma unroll
    for (int k = 1; k < 10; ++k) sel = (lane == k) ? lg[k] : sel;
    out[(size_t)b * 10 + lane] = sel - lse;
  }
}

extern "C" void kernel_launch(void* const* d_in, const int* in_sizes, int n_in,
                              void* d_out, int out_size, void* d_ws, size_t ws_size,
                              hipStream_t stream) {
  const float* x  = (const float*)d_in[0];  // (B,1,28,28) f32
  const float* qp = (const float*)d_in[1];  // (6,) f32
  const float* W  = (const float*)d_in[2];  // (10,784) f32
  const float* bi = (const float*)d_in[3];  // (10,) f32
  float* out = (float*)d_out;               // (B,10) f32

  int Bsz = in_sizes[0] / 784;

  float* W2 = (float*)d_ws;   // 7840 f32
  float* HG = W2 + 7840;      // 36 f32

  k_w2<<<NP, 64, 0, stream>>>(x, qp, W, W2, HG);
  k_main<<<(Bsz + 3) / 4, 256, 0, stream>>>(x, HG, bi, W2, out, Bsz);
}